// Round 5
// baseline (484.588 us; speedup 1.0000x reference)
//
#include <hip/hip_runtime.h>
#include <math.h>

typedef unsigned int u32;

#define NPIX 6291456

// ---------------- ws layout ----------------
//       0: madsum f32 (written by mad last block)
//     128: done[32]      (zeroed)
//     256: prefix11[32]
//     384: kk2[32]
//     512: scale[32]
//     640: mdone         (zeroed)
//    1024: cnt[32*32]    (zeroed, 128-B stride counters)
//    8192: part[64*32]   (zeroed, 128-B stride partial mad sums)
//   16384: gh[32*2048]   = 256 KB (zeroed)
//  278528: buf[32*12288] = 1.5 MB
// 1867776: arts: 4 bf16 planes of NPIX = 50.33 MB

__device__ __forceinline__ float med3f(float a, float b, float c) {
    return fmaxf(fminf(a, b), fminf(fmaxf(a, b), c));
}
__device__ __forceinline__ float med5f(float a0, float a1, float a2, float a3, float a4) {
    float mn01 = fminf(a0, a1), mx01 = fmaxf(a0, a1);
    float mn34 = fminf(a3, a4), mx34 = fmaxf(a3, a4);
    return med3f(a2, fmaxf(mn01, mn34), fminf(mx01, mx34));
}
__device__ __forceinline__ u32 packbf(float lo, float hi) {
    u32 a = __float_as_uint(lo), b = __float_as_uint(hi);
    a = (a + 0x7FFFu + ((a >> 16) & 1u)) >> 16;
    b = (b + 0x7FFFu + ((b >> 16) & 1u)) >> 16;
    return a | (b << 16);
}
__device__ __forceinline__ u32 aload(const u32* p) {
    return __hip_atomic_load(p, __ATOMIC_RELAXED, __HIP_MEMORY_SCOPE_AGENT);
}

// inclusive scan over 256 threads; wtot is 4-entry LDS; all threads must call
__device__ __forceinline__ u32 scan256(u32 v, u32* wtot) {
    int lane = threadIdx.x & 63, wid = threadIdx.x >> 6;
    u32 inc = v;
    #pragma unroll
    for (int off = 1; off < 64; off <<= 1) {
        u32 o = __shfl_up(inc, off);
        if (lane >= off) inc += o;
    }
    __syncthreads();
    if (lane == 63) wtot[wid] = inc;
    __syncthreads();
    for (int w = 0; w < wid; ++w) inc += wtot[w];
    return inc;
}

// ---------------- pass A: 11-bit LDS histogram + fused select ----------------

__global__ __launch_bounds__(256) void histA_kernel(
        const float* __restrict__ x, u32* __restrict__ gh, u32* __restrict__ done,
        u32* __restrict__ prefix11, u32* __restrict__ kk2) {
    __shared__ u32 lh[4096];   // 2048 bins x 2 lane-spread sub-bins
    __shared__ u32 wtot[4];
    __shared__ int amLast;
    int b = blockIdx.x / 12, s = blockIdx.x % 12;
    int t = threadIdx.x, lane = t & 63;
    uint4 z = make_uint4(0u, 0u, 0u, 0u);
    #pragma unroll
    for (int j = 0; j < 4; ++j) ((uint4*)lh)[t + j * 256] = z;
    __syncthreads();
    const float4* xb = (const float4*)(x + (size_t)b * 196608 + (size_t)s * 16384);
    u32 sub = (u32)(lane & 1);
    #pragma unroll
    for (int j = 0; j < 16; ++j) {
        float4 v = xb[t + j * 256];
        atomicAdd(&lh[((__float_as_uint(fabsf(v.x)) >> 20) << 1) + sub], 1u);
        atomicAdd(&lh[((__float_as_uint(fabsf(v.y)) >> 20) << 1) + sub], 1u);
        atomicAdd(&lh[((__float_as_uint(fabsf(v.z)) >> 20) << 1) + sub], 1u);
        atomicAdd(&lh[((__float_as_uint(fabsf(v.w)) >> 20) << 1) + sub], 1u);
    }
    __syncthreads();
    u32* g = gh + b * 2048;
    #pragma unroll
    for (int j = 0; j < 8; ++j) {
        int bin = t + j * 256;
        u32 c = lh[bin * 2] + lh[bin * 2 + 1];
        if (c) atomicAdd(&g[bin], c);
    }
    __syncthreads();
    if (t == 0)
        amLast = (__hip_atomic_fetch_add(&done[b], 1u, __ATOMIC_ACQ_REL,
                                         __HIP_MEMORY_SCOPE_AGENT) == 11u);
    __syncthreads();
    if (!amLast) return;
    u32 s8[8], sum = 0;
    #pragma unroll
    for (int j = 0; j < 8; ++j) { s8[j] = aload(&g[t * 8 + j]); sum += s8[j]; }
    u32 inc = scan256(sum, wtot);
    u32 exc = inc - sum;
    u32 k = 98303u;   // lower-median rank, (196608-1)/2
    if (exc <= k && k < inc) {
        u32 kr = k - exc;
        int j = 0;
        while (kr >= s8[j]) { kr -= s8[j]; ++j; }
        prefix11[b] = (u32)(t * 8 + j);
        kk2[b] = kr;
    }
}

// ---------------- pass B: wave-aggregated compaction ----------------

__global__ __launch_bounds__(256) void compactB_kernel(
        const float* __restrict__ x, const u32* __restrict__ prefix11,
        u32* __restrict__ cnt, u32* __restrict__ buf) {
    int b = blockIdx.x / 12, s = blockIdx.x % 12;
    int t = threadIdx.x, lane = t & 63;
    u32 pref = prefix11[b];
    const float4* xb = (const float4*)(x + (size_t)b * 196608 + (size_t)s * 16384);
    u32* cb = &cnt[b * 32];        // 128-B padded counter
    u32* bb = buf + b * 12288;
    #pragma unroll
    for (int j = 0; j < 16; ++j) {
        float4 v = xb[t + j * 256];
        float vv[4] = {v.x, v.y, v.z, v.w};
        u32 val[4]; int m = 0;
        #pragma unroll
        for (int e = 0; e < 4; ++e) {
            u32 bits = __float_as_uint(fabsf(vv[e]));
            if ((bits >> 20) == pref) { val[m] = bits & 0xFFFFFu; ++m; }
        }
        u32 inc = (u32)m;
        #pragma unroll
        for (int off = 1; off < 64; off <<= 1) {
            u32 o = __shfl_up(inc, off);
            if (lane >= off) inc += o;
        }
        u32 tot = __shfl(inc, 63);
        if (tot) {
            u32 base = 0;
            if (lane == 0) base = atomicAdd(cb, tot);   // 1 atomic / wave / group
            base = __shfl(base, 0);
            u32 pos = base + inc - (u32)m;
            for (int q = 0; q < m; ++q)
                if (pos + q < 12288u) bb[pos + q] = val[q];
        }
    }
}

// ---------------- pass C: in-LDS 20-bit radix select, 1 block/batch ----------------

__global__ __launch_bounds__(256) void selectC_kernel(
        const u32* __restrict__ cnt, const u32* __restrict__ buf,
        const u32* __restrict__ prefix11, const u32* __restrict__ kk2,
        float* __restrict__ scale) {
    __shared__ u32 sh[12288];
    __shared__ u32 h[128];
    __shared__ u32 wtot[4];
    __shared__ u32 sPfx, sK;
    int b = blockIdx.x, t = threadIdx.x;
    u32 m = aload(&cnt[b * 32]); if (m > 12288u) m = 12288u;
    const u32* bb = buf + b * 12288;
    for (u32 i = (u32)t; i < m; i += 256u) sh[i] = bb[i];
    if (t == 0) { sPfx = 0u; sK = kk2[b]; }
    __syncthreads();
    const int shf[3] = {13, 6, 0};
    const int wd[3]  = {7, 7, 6};
    const u32 msk[3] = {127u, 127u, 63u};
    #pragma unroll 1
    for (int rd = 0; rd < 3; ++rd) {
        u32 pfx = sPfx, k = sK;
        if (t < 128) h[t] = 0u;
        __syncthreads();
        for (u32 i = (u32)t; i < m; i += 256u) {
            u32 v = sh[i];
            if ((v >> (shf[rd] + wd[rd])) == pfx)
                atomicAdd(&h[(v >> shf[rd]) & msk[rd]], 1u);
        }
        __syncthreads();
        u32 nb = msk[rd] + 1u;
        u32 c = ((u32)t < nb) ? h[t] : 0u;
        u32 inc = scan256(c, wtot);
        u32 exc = inc - c;
        if ((u32)t < nb && exc <= k && k < inc) {
            sPfx = (pfx << wd[rd]) | (u32)t;
            sK = k - exc;
        }
        __syncthreads();
    }
    if (t == 0) scale[b] = __uint_as_float((prefix11[b] << 20) | sPfx) + 1e-8f;
}

// ---------------- denoise: full-row wave, 1 view/wave, DPP, no LDS ----------------

__device__ __forceinline__ float dpp_shl1(float v) {   // lane i <- lane i+1 (edge -> 0)
    return __uint_as_float((u32)__builtin_amdgcn_update_dpp(
        0, (int)__float_as_uint(v), 0x130, 0xF, 0xF, true));   // wave_shl:1
}
__device__ __forceinline__ float dpp_shr1(float v) {   // lane i <- lane i-1 (edge -> 0)
    return __uint_as_float((u32)__builtin_amdgcn_update_dpp(
        0, (int)__float_as_uint(v), 0x138, 0xF, 0xF, true));   // wave_shr:1
}
__device__ __forceinline__ float hub(float d, float del) {
    return d * __builtin_amdgcn_rcpf(del + fabsf(d));
}
__device__ __forceinline__ float upd(float b, float xn, float dv, float lam) {
    float t = fmaf(-lam, dv, b - xn);
    return fmaf(-0.2f, t, b);
}

__device__ __forceinline__ float4 stage4(float4 B, float4 C, float4 xn, float4& gyp,
                                         int row, float mR3, float mL0,
                                         float lam, float del) {
    float mr = (row < 255) ? 1.f : 0.f;   // wave-uniform: dy pad 0 at last row
    float m0 = (row == 0) ? 0.f : 1.f;    // div_y[0] = gy[0]
    float gy0 = hub(C.x - B.x, del) * mr;
    float gy1 = hub(C.y - B.y, del) * mr;
    float gy2 = hub(C.z - B.z, del) * mr;
    float gy3 = hub(C.w - B.w, del) * mr;
    float dv0 = gy0 - gyp.x * m0;
    float dv1 = gy1 - gyp.y * m0;
    float dv2 = gy2 - gyp.z * m0;
    float dv3 = gy3 - gyp.w * m0;
    gyp.x = gy0; gyp.y = gy1; gyp.z = gy2; gyp.w = gy3;
    float B0n = dpp_shl1(B.x);                  // next lane's col0 (= own col3+1)
    float g01 = hub(B.y - B.x, del);
    float g12 = hub(B.z - B.y, del);
    float g23 = hub(B.w - B.z, del);
    float g3n = hub(B0n - B.w, del) * mR3;      // 0 at global col 255
    float gp  = dpp_shr1(g3n) * mL0;            // prev lane's g3n; div_x[0] = gx[0]
    float4 o;
    o.x = upd(B.x, xn.x, (g01 - gp)  + dv0, lam);
    o.y = upd(B.y, xn.y, (g12 - g01) + dv1, lam);
    o.z = upd(B.z, xn.z, (g23 - g12) + dv2, lam);
    o.w = upd(B.w, xn.w, (g3n - g23) + dv3, lam);
    return o;
}

__global__ __launch_bounds__(256, 6) void denoise_kernel(
        const float* __restrict__ x, const float* __restrict__ scale,
        u32* __restrict__ arts, float4 lam4, float4 del4) {
    int t = threadIdx.x, lane = t & 63, wid = t >> 6;   // wid = view
    int img = blockIdx.x >> 4;       // 96 images
    int seg = blockIdx.x & 15;       // 16 row-segments of 16 rows
    float lam = (wid == 0) ? lam4.x : (wid == 1) ? lam4.y : (wid == 2) ? lam4.z : lam4.w;
    float del = (wid == 0) ? del4.x : (wid == 1) ? del4.y : (wid == 2) ? del4.z : del4.w;
    float mR3 = (lane == 63) ? 0.f : 1.f;
    float mL0 = (lane == 0) ? 0.f : 1.f;
    float sc = scale[img / 3];
    float inv_sc = 1.0f / sc;
    const float4* xp = (const float4*)(x + (size_t)img * 65536) + lane;  // row r: xp[r<<6]
    u32* ap = arts + (size_t)wid * (NPIX / 2) + (size_t)img * 32768 + lane * 2;

    float4 z4 = {0.f, 0.f, 0.f, 0.f};
    float4 cur1 = z4, cur2 = z4, gyp1 = z4, gyp2 = z4, gyp3 = z4;
    float4 n0 = z4, n1 = z4, n2 = z4;
    int out_lo = seg * 16, out_hi = out_lo + 15;
    int rs = (out_lo >= 3) ? out_lo - 3 : 0;   // 3-row pipeline warm-up
    int rend = out_hi + 3;                     // 3-step flush

    float4 nl = xp[rs << 6];
    nl.x *= inv_sc; nl.y *= inv_sc; nl.z *= inv_sc; nl.w *= inv_sc;
    for (int r = rs; r <= rend; ++r) {
        int rn = (r + 1 <= 255) ? r + 1 : 255;
        float4 nxt = xp[rn << 6];   // prefetch (clamped; value unused past row 255)
        int r1 = r - 1, r2 = r - 2, r3 = r - 3;
        float4 x1 = stage4(n0,   nl, n0, gyp1, r1, mR3, mL0, lam, del);
        float4 x2 = stage4(cur1, x1, n1, gyp2, r2, mR3, mL0, lam, del);
        float4 x3 = stage4(cur2, x2, n2, gyp3, r3, mR3, mL0, lam, del);
        cur1 = x1; cur2 = x2;
        if (r3 >= out_lo) {   // uniform; r3 <= out_hi by loop bound
            uint2 pk;
            pk.x = packbf(x3.x * sc, x3.y * sc);
            pk.y = packbf(x3.z * sc, x3.w * sc);
            *(uint2*)(ap + (r3 << 7)) = pk;
        }
        n2 = n1; n1 = n0; n0 = nl;
        nl.x = nxt.x * inv_sc; nl.y = nxt.y * inv_sc;
        nl.z = nxt.z * inv_sc; nl.w = nxt.w * inv_sc;
    }
}

// ---------------- mad reduction (global mad mean, fused finalize) ----------------

__global__ __launch_bounds__(256) void mad_kernel(
        const float* __restrict__ x, const u32* __restrict__ artsU,
        u32* __restrict__ part, u32* __restrict__ mdone, float* __restrict__ madsum) {
    __shared__ int amLast;
    int t = blockIdx.x * 256 + threadIdx.x;
    int lane = threadIdx.x & 63;
    float2 xv = ((const float2*)x)[t];
    u32 p0 = artsU[t];
    u32 p1 = artsU[t + NPIX / 2];
    u32 p2 = artsU[t + NPIX];
    u32 p3 = artsU[t + 3 * (NPIX / 2)];
    float msum;
    {
        float a0 = xv.x;
        float a1 = __uint_as_float(p0 << 16), a2 = __uint_as_float(p1 << 16);
        float a3 = __uint_as_float(p2 << 16), a4 = __uint_as_float(p3 << 16);
        float med = med5f(a0, a1, a2, a3, a4);
        msum = med5f(fabsf(a0 - med), fabsf(a1 - med), fabsf(a2 - med),
                     fabsf(a3 - med), fabsf(a4 - med));
    }
    {
        float a0 = xv.y;
        float a1 = __uint_as_float(p0 & 0xFFFF0000u), a2 = __uint_as_float(p1 & 0xFFFF0000u);
        float a3 = __uint_as_float(p2 & 0xFFFF0000u), a4 = __uint_as_float(p3 & 0xFFFF0000u);
        float med = med5f(a0, a1, a2, a3, a4);
        msum += med5f(fabsf(a0 - med), fabsf(a1 - med), fabsf(a2 - med),
                      fabsf(a3 - med), fabsf(a4 - med));
    }
    #pragma unroll
    for (int off = 32; off > 0; off >>= 1) msum += __shfl_down(msum, off);
    if (lane == 0) {
        int slot = (int)(((blockIdx.x << 2) | (threadIdx.x >> 6)) & 63u);
        atomicAdd((float*)&part[slot * 32], msum);   // 64 line-strided partials
    }
    __syncthreads();
    if (threadIdx.x == 0)
        amLast = (__hip_atomic_fetch_add(mdone, 1u, __ATOMIC_ACQ_REL,
                                         __HIP_MEMORY_SCOPE_AGENT) == (u32)(gridDim.x - 1));
    __syncthreads();
    if (!amLast) return;
    if (threadIdx.x < 64) {
        float v = __uint_as_float(aload(&part[threadIdx.x * 32]));
        #pragma unroll
        for (int off = 32; off > 0; off >>= 1) v += __shfl_down(v, off);
        if (threadIdx.x == 0) *madsum = v;
    }
}

// ---------------- fusion ----------------

__global__ __launch_bounds__(256) void fuse_kernel(
        const float* __restrict__ x, const u32* __restrict__ artsU,
        const float* __restrict__ madsum, float* __restrict__ out) {
    int t = blockIdx.x * 256 + threadIdx.x;
    float floorv = 0.1f * (*madsum) * (1.0f / 6291456.0f);
    float2 xv = ((const float2*)x)[t];
    u32 p0 = artsU[t];
    u32 p1 = artsU[t + NPIX / 2];
    u32 p2 = artsU[t + NPIX];
    u32 p3 = artsU[t + 3 * (NPIX / 2)];
    float2 o;
#define FUSE1(res, A0, SH) { \
        float a0 = A0; \
        float a1 = __uint_as_float(SH(p0)), a2 = __uint_as_float(SH(p1)); \
        float a3 = __uint_as_float(SH(p2)), a4 = __uint_as_float(SH(p3)); \
        float med = med5f(a0, a1, a2, a3, a4); \
        float d0 = fabsf(a0 - med), d1 = fabsf(a1 - med), d2 = fabsf(a2 - med); \
        float d3 = fabsf(a3 - med), d4 = fabsf(a4 - med); \
        float mad = med5f(d0, d1, d2, d3, d4); \
        float m = fmaxf(mad, floorv); \
        float inv = 0.5f / m; \
        float w0 = __expf(-d0 * inv), w1 = __expf(-d1 * inv), w2 = __expf(-d2 * inv); \
        float w3 = __expf(-d3 * inv), w4 = __expf(-d4 * inv); \
        float swt = w0 + w1 + w2 + w3 + w4; \
        float sva = fmaf(w0, a0, fmaf(w1, a1, fmaf(w2, a2, fmaf(w3, a3, w4 * a4)))); \
        res = sva / (swt + 1e-8f); \
    }
#define LO16(u) ((u) << 16)
#define HI16(u) ((u) & 0xFFFF0000u)
    FUSE1(o.x, xv.x, LO16);
    FUSE1(o.y, xv.y, HI16);
#undef FUSE1
#undef LO16
#undef HI16
    ((float2*)out)[t] = o;
}

// ---------------- launch ----------------

extern "C" void kernel_launch(void* const* d_in, const int* in_sizes, int n_in,
                              void* d_out, int out_size, void* d_ws, size_t ws_size,
                              hipStream_t stream) {
    const float* x = (const float*)d_in[0];
    float* out = (float*)d_out;
    char* ws = (char*)d_ws;
    float* madsum  = (float*)ws;
    u32* done      = (u32*)(ws + 128);
    u32* prefix11  = (u32*)(ws + 256);
    u32* kk2       = (u32*)(ws + 384);
    float* scale   = (float*)(ws + 512);
    u32* mdone     = (u32*)(ws + 640);
    u32* cnt       = (u32*)(ws + 1024);
    u32* part      = (u32*)(ws + 8192);
    u32* gh        = (u32*)(ws + 16384);
    u32* buf       = (u32*)(ws + 278528);
    u32* artsU     = (u32*)(ws + 1867776);

    hipMemsetAsync(ws, 0, 278528, stream);   // control + partials + 256 KB histogram

    histA_kernel<<<384, 256, 0, stream>>>(x, gh, done, prefix11, kk2);
    compactB_kernel<<<384, 256, 0, stream>>>(x, prefix11, cnt, buf);
    selectC_kernel<<<32, 256, 0, stream>>>(cnt, buf, prefix11, kk2, scale);

    float lamf[4], delf[4];
    for (int i = 0; i < 4; ++i) {
        double lam = 0.025 + 0.05 * (double)i / 3.0;
        lamf[i] = (float)lam;
        delf[i] = (float)(0.01 * sqrt(lam / (0.05 + 1e-8)));
    }
    float4 lam4 = make_float4(lamf[0], lamf[1], lamf[2], lamf[3]);
    float4 del4 = make_float4(delf[0], delf[1], delf[2], delf[3]);

    denoise_kernel<<<1536, 256, 0, stream>>>(x, scale, artsU, lam4, del4);
    mad_kernel<<<12288, 256, 0, stream>>>(x, artsU, part, mdone, madsum);
    fuse_kernel<<<12288, 256, 0, stream>>>(x, artsU, madsum, out);
}

// Round 6
// 224.122 us; speedup vs baseline: 2.1622x; 2.1622x over previous
//
#include <hip/hip_runtime.h>
#include <math.h>

typedef unsigned int u32;

#define NPIX 6291456

// ---------------- ws layout ----------------
//       0: madsum f32 (written by reduce_kernel)
//     128: done[32]        (zeroed)
//     256: prefix11[32]
//     384: kk2[32]
//     512: scale[32]
//    1024: cnt[32*12]      (plain-stored by compactB)
//    8192: part[12288] f32 (plain-stored by mad blocks)
//   57344: gh[32*2048]     = 256 KB (zeroed)
//  319488: buf[32*12*2048] = 3 MB (per-(b,s) regions)
// 3465216: arts: 4 bf16 planes of NPIX = 50.33 MB

__device__ __forceinline__ float med3f(float a, float b, float c) {
    return fmaxf(fminf(a, b), fminf(fmaxf(a, b), c));
}
__device__ __forceinline__ float med5f(float a0, float a1, float a2, float a3, float a4) {
    float mn01 = fminf(a0, a1), mx01 = fmaxf(a0, a1);
    float mn34 = fminf(a3, a4), mx34 = fmaxf(a3, a4);
    return med3f(a2, fmaxf(mn01, mn34), fminf(mx01, mx34));
}
__device__ __forceinline__ u32 packbf(float lo, float hi) {
    u32 a = __float_as_uint(lo), b = __float_as_uint(hi);
    a = (a + 0x7FFFu + ((a >> 16) & 1u)) >> 16;
    b = (b + 0x7FFFu + ((b >> 16) & 1u)) >> 16;
    return a | (b << 16);
}
__device__ __forceinline__ u32 aload(const u32* p) {
    return __hip_atomic_load(p, __ATOMIC_RELAXED, __HIP_MEMORY_SCOPE_AGENT);
}

// inclusive scan over 256 threads; wtot is 4-entry LDS; all threads must call
__device__ __forceinline__ u32 scan256(u32 v, u32* wtot) {
    int lane = threadIdx.x & 63, wid = threadIdx.x >> 6;
    u32 inc = v;
    #pragma unroll
    for (int off = 1; off < 64; off <<= 1) {
        u32 o = __shfl_up(inc, off);
        if (lane >= off) inc += o;
    }
    __syncthreads();
    if (lane == 63) wtot[wid] = inc;
    __syncthreads();
    for (int w = 0; w < wid; ++w) inc += wtot[w];
    return inc;
}

// ---------------- pass A: 11-bit LDS histogram + fused select ----------------

__global__ __launch_bounds__(256) void histA_kernel(
        const float* __restrict__ x, u32* __restrict__ gh, u32* __restrict__ done,
        u32* __restrict__ prefix11, u32* __restrict__ kk2) {
    __shared__ u32 lh[16384];   // 2048 bins x 8 lane-spread sub-bins
    __shared__ u32 wtot[4];
    __shared__ int amLast;
    int b = blockIdx.x / 12, s = blockIdx.x % 12;
    int t = threadIdx.x, lane = t & 63;
    uint4 z = make_uint4(0u, 0u, 0u, 0u);
    #pragma unroll
    for (int j = 0; j < 16; ++j) ((uint4*)lh)[t + j * 256] = z;
    __syncthreads();
    const float4* xb = (const float4*)(x + (size_t)b * 196608 + (size_t)s * 16384);
    u32 sub = (u32)(lane & 7);
    #pragma unroll
    for (int j = 0; j < 16; ++j) {
        float4 v = xb[t + j * 256];
        atomicAdd(&lh[((__float_as_uint(fabsf(v.x)) >> 20) << 3) + sub], 1u);
        atomicAdd(&lh[((__float_as_uint(fabsf(v.y)) >> 20) << 3) + sub], 1u);
        atomicAdd(&lh[((__float_as_uint(fabsf(v.z)) >> 20) << 3) + sub], 1u);
        atomicAdd(&lh[((__float_as_uint(fabsf(v.w)) >> 20) << 3) + sub], 1u);
    }
    __syncthreads();
    u32* g = gh + b * 2048;
    #pragma unroll
    for (int j = 0; j < 8; ++j) {
        int bin = t + j * 256;
        u32 c = 0;
        #pragma unroll
        for (int k = 0; k < 8; ++k) c += lh[bin * 8 + k];
        if (c) atomicAdd(&g[bin], c);
    }
    __syncthreads();
    if (t == 0)
        amLast = (__hip_atomic_fetch_add(&done[b], 1u, __ATOMIC_ACQ_REL,
                                         __HIP_MEMORY_SCOPE_AGENT) == 11u);
    __syncthreads();
    if (!amLast) return;
    u32 s8[8], sum = 0;
    #pragma unroll
    for (int j = 0; j < 8; ++j) { s8[j] = aload(&g[t * 8 + j]); sum += s8[j]; }
    u32 inc = scan256(sum, wtot);
    u32 exc = inc - sum;
    u32 k = 98303u;   // lower-median rank, (196608-1)/2
    if (exc <= k && k < inc) {
        u32 kr = k - exc;
        int j = 0;
        while (kr >= s8[j]) { kr -= s8[j]; ++j; }
        prefix11[b] = (u32)(t * 8 + j);
        kk2[b] = kr;
    }
}

// ---------------- pass B: compaction into per-block regions (no global atomics) ----

__global__ __launch_bounds__(256) void compactB_kernel(
        const float* __restrict__ x, const u32* __restrict__ prefix11,
        u32* __restrict__ cnt, u32* __restrict__ buf) {
    __shared__ u32 lcnt;
    int b = blockIdx.x / 12, s = blockIdx.x % 12;
    int t = threadIdx.x, lane = t & 63;
    if (t == 0) lcnt = 0u;
    __syncthreads();
    u32 pref = prefix11[b];
    const float4* xb = (const float4*)(x + (size_t)b * 196608 + (size_t)s * 16384);
    u32* bb = buf + ((size_t)b * 12 + s) * 2048;
    #pragma unroll
    for (int j = 0; j < 16; ++j) {
        float4 v = xb[t + j * 256];
        float vv[4] = {v.x, v.y, v.z, v.w};
        u32 val[4]; int m = 0;
        #pragma unroll
        for (int e = 0; e < 4; ++e) {
            u32 bits = __float_as_uint(fabsf(vv[e]));
            if ((bits >> 20) == pref) { val[m] = bits & 0xFFFFFu; ++m; }
        }
        u32 inc = (u32)m;
        #pragma unroll
        for (int off = 1; off < 64; off <<= 1) {
            u32 o = __shfl_up(inc, off);
            if (lane >= off) inc += o;
        }
        u32 tot = __shfl(inc, 63);
        if (tot) {
            u32 base = 0;
            if (lane == 0) base = atomicAdd(&lcnt, tot);   // LDS atomic only
            base = __shfl(base, 0);
            u32 pos = base + inc - (u32)m;
            for (int q = 0; q < m; ++q)
                if (pos + q < 2048u) bb[pos + q] = val[q];
        }
    }
    __syncthreads();
    if (t == 0) cnt[b * 12 + s] = (lcnt < 2048u) ? lcnt : 2048u;
}

// ---------------- pass C: in-LDS 20-bit radix select, 1 block/batch ----------------

__global__ __launch_bounds__(256) void selectC_kernel(
        const u32* __restrict__ cnt, const u32* __restrict__ buf,
        const u32* __restrict__ prefix11, const u32* __restrict__ kk2,
        float* __restrict__ scale) {
    __shared__ u32 sh[16384];
    __shared__ u32 h[128];
    __shared__ u32 wtot[4];
    __shared__ u32 sPfx, sK;
    int b = blockIdx.x, t = threadIdx.x;
    u32 off = 0;
    for (int s = 0; s < 12; ++s) {
        u32 c = cnt[b * 12 + s];
        if (off + c > 16384u) c = 16384u - off;
        const u32* bb = buf + ((size_t)b * 12 + s) * 2048;
        for (u32 i = (u32)t; i < c; i += 256u) sh[off + i] = bb[i];
        off += c;
    }
    u32 m = off;
    if (t == 0) { sPfx = 0u; sK = kk2[b]; }
    __syncthreads();
    const int shf[3] = {13, 6, 0};
    const int wd[3]  = {7, 7, 6};
    const u32 msk[3] = {127u, 127u, 63u};
    #pragma unroll 1
    for (int rd = 0; rd < 3; ++rd) {
        u32 pfx = sPfx, k = sK;
        if (t < 128) h[t] = 0u;
        __syncthreads();
        for (u32 i = (u32)t; i < m; i += 256u) {
            u32 v = sh[i];
            if ((v >> (shf[rd] + wd[rd])) == pfx)
                atomicAdd(&h[(v >> shf[rd]) & msk[rd]], 1u);
        }
        __syncthreads();
        u32 nb = msk[rd] + 1u;
        u32 c = ((u32)t < nb) ? h[t] : 0u;
        u32 inc = scan256(c, wtot);
        u32 exc = inc - c;
        if ((u32)t < nb && exc <= k && k < inc) {
            sPfx = (pfx << wd[rd]) | (u32)t;
            sK = k - exc;
        }
        __syncthreads();
    }
    if (t == 0) scale[b] = __uint_as_float((prefix11[b] << 20) | sPfx) + 1e-8f;
}

// ---------------- denoise: full-row wave, 1 view/wave, DPP, no LDS ----------------

__device__ __forceinline__ float dpp_shl1(float v) {   // lane i <- lane i+1 (edge -> 0)
    return __uint_as_float((u32)__builtin_amdgcn_update_dpp(
        0, (int)__float_as_uint(v), 0x130, 0xF, 0xF, true));   // wave_shl:1
}
__device__ __forceinline__ float dpp_shr1(float v) {   // lane i <- lane i-1 (edge -> 0)
    return __uint_as_float((u32)__builtin_amdgcn_update_dpp(
        0, (int)__float_as_uint(v), 0x138, 0xF, 0xF, true));   // wave_shr:1
}
__device__ __forceinline__ float hub(float d, float del) {
    return d * __builtin_amdgcn_rcpf(del + fabsf(d));
}
__device__ __forceinline__ float upd(float b, float xn, float dv, float lam) {
    float t = fmaf(-lam, dv, b - xn);
    return fmaf(-0.2f, t, b);
}

__device__ __forceinline__ float4 stage4(float4 B, float4 C, float4 xn, float4& gyp,
                                         int row, float mR3, float mL0,
                                         float lam, float del) {
    float mr = (row < 255) ? 1.f : 0.f;   // wave-uniform: dy pad 0 at last row
    float m0 = (row == 0) ? 0.f : 1.f;    // div_y[0] = gy[0]
    float gy0 = hub(C.x - B.x, del) * mr;
    float gy1 = hub(C.y - B.y, del) * mr;
    float gy2 = hub(C.z - B.z, del) * mr;
    float gy3 = hub(C.w - B.w, del) * mr;
    float dv0 = gy0 - gyp.x * m0;
    float dv1 = gy1 - gyp.y * m0;
    float dv2 = gy2 - gyp.z * m0;
    float dv3 = gy3 - gyp.w * m0;
    gyp.x = gy0; gyp.y = gy1; gyp.z = gy2; gyp.w = gy3;
    float B0n = dpp_shl1(B.x);                  // next lane's col0 (= own col3+1)
    float g01 = hub(B.y - B.x, del);
    float g12 = hub(B.z - B.y, del);
    float g23 = hub(B.w - B.z, del);
    float g3n = hub(B0n - B.w, del) * mR3;      // 0 at global col 255
    float gp  = dpp_shr1(g3n) * mL0;            // prev lane's g3n; div_x[0] = gx[0]
    float4 o;
    o.x = upd(B.x, xn.x, (g01 - gp)  + dv0, lam);
    o.y = upd(B.y, xn.y, (g12 - g01) + dv1, lam);
    o.z = upd(B.z, xn.z, (g23 - g12) + dv2, lam);
    o.w = upd(B.w, xn.w, (g3n - g23) + dv3, lam);
    return o;
}

__global__ __launch_bounds__(256, 6) void denoise_kernel(
        const float* __restrict__ x, const float* __restrict__ scale,
        u32* __restrict__ arts, float4 lam4, float4 del4) {
    int t = threadIdx.x, lane = t & 63, wid = t >> 6;   // wid = view
    int img = blockIdx.x >> 4;       // 96 images
    int seg = blockIdx.x & 15;       // 16 row-segments of 16 rows
    float lam = (wid == 0) ? lam4.x : (wid == 1) ? lam4.y : (wid == 2) ? lam4.z : lam4.w;
    float del = (wid == 0) ? del4.x : (wid == 1) ? del4.y : (wid == 2) ? del4.z : del4.w;
    float mR3 = (lane == 63) ? 0.f : 1.f;
    float mL0 = (lane == 0) ? 0.f : 1.f;
    float sc = scale[img / 3];
    float inv_sc = 1.0f / sc;
    const float4* xp = (const float4*)(x + (size_t)img * 65536) + lane;  // row r: xp[r<<6]
    u32* ap = arts + (size_t)wid * (NPIX / 2) + (size_t)img * 32768 + lane * 2;

    float4 z4 = {0.f, 0.f, 0.f, 0.f};
    float4 cur1 = z4, cur2 = z4, gyp1 = z4, gyp2 = z4, gyp3 = z4;
    float4 n0 = z4, n1 = z4, n2 = z4;
    int out_lo = seg * 16, out_hi = out_lo + 15;
    int rs = (out_lo >= 3) ? out_lo - 3 : 0;   // 3-row pipeline warm-up
    int rend = out_hi + 3;                     // 3-step flush

    float4 nl = xp[rs << 6];
    nl.x *= inv_sc; nl.y *= inv_sc; nl.z *= inv_sc; nl.w *= inv_sc;
    for (int r = rs; r <= rend; ++r) {
        int rn = (r + 1 <= 255) ? r + 1 : 255;
        float4 nxt = xp[rn << 6];   // prefetch (clamped; value unused past row 255)
        int r1 = r - 1, r2 = r - 2, r3 = r - 3;
        float4 x1 = stage4(n0,   nl, n0, gyp1, r1, mR3, mL0, lam, del);
        float4 x2 = stage4(cur1, x1, n1, gyp2, r2, mR3, mL0, lam, del);
        float4 x3 = stage4(cur2, x2, n2, gyp3, r3, mR3, mL0, lam, del);
        cur1 = x1; cur2 = x2;
        if (r3 >= out_lo) {   // uniform; r3 <= out_hi by loop bound
            uint2 pk;
            pk.x = packbf(x3.x * sc, x3.y * sc);
            pk.y = packbf(x3.z * sc, x3.w * sc);
            *(uint2*)(ap + (r3 << 7)) = pk;
        }
        n2 = n1; n1 = n0; n0 = nl;
        nl.x = nxt.x * inv_sc; nl.y = nxt.y * inv_sc;
        nl.z = nxt.z * inv_sc; nl.w = nxt.w * inv_sc;
    }
}

// ---------------- mad reduction: per-block partial, plain store ----------------

__global__ __launch_bounds__(256) void mad_kernel(
        const float* __restrict__ x, const u32* __restrict__ artsU,
        float* __restrict__ part) {
    __shared__ float red[4];
    int t = blockIdx.x * 256 + threadIdx.x;
    int lane = threadIdx.x & 63;
    float2 xv = ((const float2*)x)[t];
    u32 p0 = artsU[t];
    u32 p1 = artsU[t + NPIX / 2];
    u32 p2 = artsU[t + NPIX];
    u32 p3 = artsU[t + 3 * (NPIX / 2)];
    float msum;
    {
        float a0 = xv.x;
        float a1 = __uint_as_float(p0 << 16), a2 = __uint_as_float(p1 << 16);
        float a3 = __uint_as_float(p2 << 16), a4 = __uint_as_float(p3 << 16);
        float med = med5f(a0, a1, a2, a3, a4);
        msum = med5f(fabsf(a0 - med), fabsf(a1 - med), fabsf(a2 - med),
                     fabsf(a3 - med), fabsf(a4 - med));
    }
    {
        float a0 = xv.y;
        float a1 = __uint_as_float(p0 & 0xFFFF0000u), a2 = __uint_as_float(p1 & 0xFFFF0000u);
        float a3 = __uint_as_float(p2 & 0xFFFF0000u), a4 = __uint_as_float(p3 & 0xFFFF0000u);
        float med = med5f(a0, a1, a2, a3, a4);
        msum += med5f(fabsf(a0 - med), fabsf(a1 - med), fabsf(a2 - med),
                      fabsf(a3 - med), fabsf(a4 - med));
    }
    #pragma unroll
    for (int off = 32; off > 0; off >>= 1) msum += __shfl_down(msum, off);
    if (lane == 0) red[threadIdx.x >> 6] = msum;
    __syncthreads();
    if (threadIdx.x == 0)
        part[blockIdx.x] = red[0] + red[1] + red[2] + red[3];
}

__global__ __launch_bounds__(256) void reduce_kernel(
        const float* __restrict__ part, float* __restrict__ madsum) {
    __shared__ float red[4];
    int t = threadIdx.x, lane = t & 63;
    float v = 0.f;
    for (int i = t; i < 12288; i += 256) v += part[i];
    #pragma unroll
    for (int off = 32; off > 0; off >>= 1) v += __shfl_down(v, off);
    if (lane == 0) red[t >> 6] = v;
    __syncthreads();
    if (t == 0) *madsum = red[0] + red[1] + red[2] + red[3];
}

// ---------------- fusion ----------------

__global__ __launch_bounds__(256) void fuse_kernel(
        const float* __restrict__ x, const u32* __restrict__ artsU,
        const float* __restrict__ madsum, float* __restrict__ out) {
    int t = blockIdx.x * 256 + threadIdx.x;
    float floorv = 0.1f * (*madsum) * (1.0f / 6291456.0f);
    float2 xv = ((const float2*)x)[t];
    u32 p0 = artsU[t];
    u32 p1 = artsU[t + NPIX / 2];
    u32 p2 = artsU[t + NPIX];
    u32 p3 = artsU[t + 3 * (NPIX / 2)];
    float2 o;
#define FUSE1(res, A0, SH) { \
        float a0 = A0; \
        float a1 = __uint_as_float(SH(p0)), a2 = __uint_as_float(SH(p1)); \
        float a3 = __uint_as_float(SH(p2)), a4 = __uint_as_float(SH(p3)); \
        float med = med5f(a0, a1, a2, a3, a4); \
        float d0 = fabsf(a0 - med), d1 = fabsf(a1 - med), d2 = fabsf(a2 - med); \
        float d3 = fabsf(a3 - med), d4 = fabsf(a4 - med); \
        float mad = med5f(d0, d1, d2, d3, d4); \
        float m = fmaxf(mad, floorv); \
        float inv = 0.5f / m; \
        float w0 = __expf(-d0 * inv), w1 = __expf(-d1 * inv), w2 = __expf(-d2 * inv); \
        float w3 = __expf(-d3 * inv), w4 = __expf(-d4 * inv); \
        float swt = w0 + w1 + w2 + w3 + w4; \
        float sva = fmaf(w0, a0, fmaf(w1, a1, fmaf(w2, a2, fmaf(w3, a3, w4 * a4)))); \
        res = sva / (swt + 1e-8f); \
    }
#define LO16(u) ((u) << 16)
#define HI16(u) ((u) & 0xFFFF0000u)
    FUSE1(o.x, xv.x, LO16);
    FUSE1(o.y, xv.y, HI16);
#undef FUSE1
#undef LO16
#undef HI16
    ((float2*)out)[t] = o;
}

// ---------------- launch ----------------

extern "C" void kernel_launch(void* const* d_in, const int* in_sizes, int n_in,
                              void* d_out, int out_size, void* d_ws, size_t ws_size,
                              hipStream_t stream) {
    const float* x = (const float*)d_in[0];
    float* out = (float*)d_out;
    char* ws = (char*)d_ws;
    float* madsum  = (float*)ws;
    u32* done      = (u32*)(ws + 128);
    u32* prefix11  = (u32*)(ws + 256);
    u32* kk2       = (u32*)(ws + 384);
    float* scale   = (float*)(ws + 512);
    u32* cnt       = (u32*)(ws + 1024);
    float* part    = (float*)(ws + 8192);
    u32* gh        = (u32*)(ws + 57344);
    u32* buf       = (u32*)(ws + 319488);
    u32* artsU     = (u32*)(ws + 3465216);

    hipMemsetAsync(ws, 0, 319488, stream);   // control + 256 KB histogram

    histA_kernel<<<384, 256, 0, stream>>>(x, gh, done, prefix11, kk2);
    compactB_kernel<<<384, 256, 0, stream>>>(x, prefix11, cnt, buf);
    selectC_kernel<<<32, 256, 0, stream>>>(cnt, buf, prefix11, kk2, scale);

    float lamf[4], delf[4];
    for (int i = 0; i < 4; ++i) {
        double lam = 0.025 + 0.05 * (double)i / 3.0;
        lamf[i] = (float)lam;
        delf[i] = (float)(0.01 * sqrt(lam / (0.05 + 1e-8)));
    }
    float4 lam4 = make_float4(lamf[0], lamf[1], lamf[2], lamf[3]);
    float4 del4 = make_float4(delf[0], delf[1], delf[2], delf[3]);

    denoise_kernel<<<1536, 256, 0, stream>>>(x, scale, artsU, lam4, del4);
    mad_kernel<<<12288, 256, 0, stream>>>(x, artsU, part);
    reduce_kernel<<<1, 256, 0, stream>>>(part, madsum);
    fuse_kernel<<<12288, 256, 0, stream>>>(x, artsU, madsum, out);
}

// Round 7
// 214.545 us; speedup vs baseline: 2.2587x; 1.0446x over previous
//
#include <hip/hip_runtime.h>
#include <math.h>

typedef unsigned int u32;

#define NPIX 6291456

// ---------------- ws layout ----------------
//     0: scale[32] f32   (written by median_kernel)
//   128: madsum f32      (zeroed by median_kernel, atomicAdd by denoise)
//   256: arts, 4 bf16 planes of NPIX packed as u32[2*NPIX] = 50.33 MB

__device__ __forceinline__ float med3f(float a, float b, float c) {
    return fmaxf(fminf(a, b), fminf(fmaxf(a, b), c));
}
__device__ __forceinline__ float med5f(float a0, float a1, float a2, float a3, float a4) {
    float mn01 = fminf(a0, a1), mx01 = fmaxf(a0, a1);
    float mn34 = fminf(a3, a4), mx34 = fmaxf(a3, a4);
    return med3f(a2, fmaxf(mn01, mn34), fminf(mx01, mx34));
}
__device__ __forceinline__ u32 packbf(float lo, float hi) {
    u32 a = __float_as_uint(lo), b = __float_as_uint(hi);
    a = (a + 0x7FFFu + ((a >> 16) & 1u)) >> 16;
    b = (b + 0x7FFFu + ((b >> 16) & 1u)) >> 16;
    return a | (b << 16);
}

// inclusive scan over 1024 threads; wtot = 16-entry LDS; all threads must call
__device__ __forceinline__ u32 scan1024(u32 v, u32* wtot) {
    int lane = threadIdx.x & 63, wid = threadIdx.x >> 6;
    u32 inc = v;
    #pragma unroll
    for (int off = 1; off < 64; off <<= 1) {
        u32 o = __shfl_up(inc, off);
        if (lane >= off) inc += o;
    }
    __syncthreads();                 // WAR protection for wtot reuse
    if (lane == 63) wtot[wid] = inc;
    __syncthreads();
    for (int w = 0; w < wid; ++w) inc += wtot[w];
    return inc;
}

// ---------------- median: one block per batch, single dispatch ----------------

__global__ __launch_bounds__(1024) void median_kernel(
        const float* __restrict__ x, float* __restrict__ scale,
        float* __restrict__ madsum) {
    __shared__ u32 lh[16384];    // 4096 bins x 4 lane-spread subs (64 KB)
    __shared__ u32 sbuf[8192];   // bin-member suffixes (32 KB)
    __shared__ u32 h[128];
    __shared__ u32 wtot[16];
    __shared__ u32 sBin, sKr, lcnt, sPfx, sK;
    int b = blockIdx.x, t = threadIdx.x, lane = t & 63;
    uint4 z = make_uint4(0u, 0u, 0u, 0u);
    #pragma unroll
    for (int j = 0; j < 4; ++j) ((uint4*)lh)[t + j * 1024] = z;
    if (t == 0) lcnt = 0u;
    __syncthreads();
    const float4* xb = (const float4*)(x + (size_t)b * 196608);
    u32 sub = (u32)(lane & 3);
    // sweep 1: 12-bit histogram (exp + 4 mantissa bits)
    #pragma unroll 4
    for (int i = 0; i < 48; ++i) {
        float4 v = xb[t + i * 1024];
        atomicAdd(&lh[((__float_as_uint(fabsf(v.x)) >> 19) << 2) + sub], 1u);
        atomicAdd(&lh[((__float_as_uint(fabsf(v.y)) >> 19) << 2) + sub], 1u);
        atomicAdd(&lh[((__float_as_uint(fabsf(v.z)) >> 19) << 2) + sub], 1u);
        atomicAdd(&lh[((__float_as_uint(fabsf(v.w)) >> 19) << 2) + sub], 1u);
    }
    __syncthreads();
    // select the bin containing global rank 98303 (lower median)
    u32 s4[4], sum = 0;
    #pragma unroll
    for (int j = 0; j < 4; ++j) {
        int bin = t * 4 + j;
        s4[j] = lh[bin * 4] + lh[bin * 4 + 1] + lh[bin * 4 + 2] + lh[bin * 4 + 3];
        sum += s4[j];
    }
    u32 inc = scan1024(sum, wtot);
    u32 exc = inc - sum;
    u32 k = 98303u;
    if (exc <= k && k < inc) {
        u32 kr = k - exc;
        int j = 0;
        while (kr >= s4[j]) { kr -= s4[j]; ++j; }
        sBin = (u32)(t * 4 + j);
        sKr = kr;
    }
    __syncthreads();
    u32 bin = sBin, kk = sKr;
    // sweep 2 (L2-resident): compact members' 19-bit suffixes into LDS
    #pragma unroll 2
    for (int i = 0; i < 48; ++i) {
        float4 v = xb[t + i * 1024];
        float vv[4] = {v.x, v.y, v.z, v.w};
        u32 val[4]; int m = 0;
        #pragma unroll
        for (int e = 0; e < 4; ++e) {
            u32 bits = __float_as_uint(fabsf(vv[e]));
            if ((bits >> 19) == bin) { val[m] = bits & 0x7FFFFu; ++m; }
        }
        u32 wi = (u32)m;
        #pragma unroll
        for (int off = 1; off < 64; off <<= 1) {
            u32 o = __shfl_up(wi, off);
            if (lane >= off) wi += o;
        }
        u32 tot = __shfl(wi, 63);
        if (tot) {
            u32 base = 0;
            if (lane == 0) base = atomicAdd(&lcnt, tot);
            base = __shfl(base, 0);
            u32 pos = base + wi - (u32)m;
            for (int q = 0; q < m; ++q)
                if (pos + q < 8192u) sbuf[pos + q] = val[q];
        }
    }
    __syncthreads();
    u32 m = lcnt; if (m > 8192u) m = 8192u;
    if (t == 0) { sPfx = 0u; sK = kk; }
    __syncthreads();
    // 3-round radix select on the 19-bit suffix: widths 7,6,6
    const int shf[3] = {12, 6, 0};
    const int wd[3]  = {7, 6, 6};
    const u32 msk[3] = {127u, 63u, 63u};
    #pragma unroll 1
    for (int rd = 0; rd < 3; ++rd) {
        u32 pfx = sPfx, k2 = sK;
        if (t < 128) h[t] = 0u;
        __syncthreads();
        for (u32 i = (u32)t; i < m; i += 1024u) {
            u32 v = sbuf[i];
            if ((v >> (shf[rd] + wd[rd])) == pfx)
                atomicAdd(&h[(v >> shf[rd]) & msk[rd]], 1u);
        }
        __syncthreads();
        u32 nb = msk[rd] + 1u;
        u32 c = ((u32)t < nb) ? h[t] : 0u;
        u32 inc2 = scan1024(c, wtot);
        u32 exc2 = inc2 - c;
        if ((u32)t < nb && exc2 <= k2 && k2 < inc2) {
            sPfx = (pfx << wd[rd]) | (u32)t;
            sK = k2 - exc2;
        }
        __syncthreads();
    }
    if (t == 0) {
        scale[b] = __uint_as_float((bin << 19) | sPfx) + 1e-8f;
        if (b == 0) *madsum = 0.0f;
    }
}

// ---------------- denoise: full-row wave, 1 view/wave, DPP, unscaled domain ------
// identity: huber_tv(x/s, lam, del) * s == huber_tv(x, lam*s, del*s)

__device__ __forceinline__ float dpp_shl1(float v) {   // lane i <- lane i+1 (edge -> 0)
    return __uint_as_float((u32)__builtin_amdgcn_update_dpp(
        0, (int)__float_as_uint(v), 0x130, 0xF, 0xF, true));   // wave_shl:1
}
__device__ __forceinline__ float dpp_shr1(float v) {   // lane i <- lane i-1 (edge -> 0)
    return __uint_as_float((u32)__builtin_amdgcn_update_dpp(
        0, (int)__float_as_uint(v), 0x138, 0xF, 0xF, true));   // wave_shr:1
}
__device__ __forceinline__ float hub(float d, float del) {
    return d * __builtin_amdgcn_rcpf(del + fabsf(d));
}
__device__ __forceinline__ float upd(float b, float xn, float dv, float lam) {
    float t = fmaf(-lam, dv, b - xn);
    return fmaf(-0.2f, t, b);
}

__device__ __forceinline__ float4 stage4(float4 B, float4 C, float4 xn, float4& gyp,
                                         int row, float mR3, float mL0,
                                         float lam, float del) {
    float mr = (row < 255) ? 1.f : 0.f;   // wave-uniform: dy pad 0 at last row
    float m0 = (row == 0) ? 0.f : 1.f;    // div_y[0] = gy[0]
    float gy0 = hub(C.x - B.x, del) * mr;
    float gy1 = hub(C.y - B.y, del) * mr;
    float gy2 = hub(C.z - B.z, del) * mr;
    float gy3 = hub(C.w - B.w, del) * mr;
    float dv0 = gy0 - gyp.x * m0;
    float dv1 = gy1 - gyp.y * m0;
    float dv2 = gy2 - gyp.z * m0;
    float dv3 = gy3 - gyp.w * m0;
    gyp.x = gy0; gyp.y = gy1; gyp.z = gy2; gyp.w = gy3;
    float B0n = dpp_shl1(B.x);                  // next lane's col0 (= own col3+1)
    float g01 = hub(B.y - B.x, del);
    float g12 = hub(B.z - B.y, del);
    float g23 = hub(B.w - B.z, del);
    float g3n = hub(B0n - B.w, del) * mR3;      // 0 at global col 255
    float gp  = dpp_shr1(g3n) * mL0;            // prev lane's g3n; div_x[0] = gx[0]
    float4 o;
    o.x = upd(B.x, xn.x, (g01 - gp)  + dv0, lam);
    o.y = upd(B.y, xn.y, (g12 - g01) + dv1, lam);
    o.z = upd(B.z, xn.z, (g23 - g12) + dv2, lam);
    o.w = upd(B.w, xn.w, (g3n - g23) + dv3, lam);
    return o;
}

__global__ __launch_bounds__(256, 6) void denoise_kernel(
        const float* __restrict__ x, const float* __restrict__ scale,
        u32* __restrict__ arts, float* __restrict__ madsum,
        float4 lam4, float4 del4) {
    __shared__ float sex[5][256];   // [0]=x row, [1..4]=view rows (f32)
    __shared__ float red[4];
    int t = threadIdx.x, lane = t & 63, wid = t >> 6;   // wid = view
    int img = blockIdx.x >> 4;       // 96 images
    int seg = blockIdx.x & 15;       // 16 row-segments of 16 rows
    float sc = scale[img / 3];
    float lam = ((wid == 0) ? lam4.x : (wid == 1) ? lam4.y : (wid == 2) ? lam4.z : lam4.w) * sc;
    float del = ((wid == 0) ? del4.x : (wid == 1) ? del4.y : (wid == 2) ? del4.z : del4.w) * sc;
    float mR3 = (lane == 63) ? 0.f : 1.f;
    float mL0 = (lane == 0) ? 0.f : 1.f;
    const float4* xp = (const float4*)(x + (size_t)img * 65536) + lane;  // row r: xp[r<<6]
    u32* ap = arts + (size_t)wid * (NPIX / 2) + (size_t)img * 32768 + lane * 2;

    float4 z4 = {0.f, 0.f, 0.f, 0.f};
    float4 cur1 = z4, cur2 = z4, gyp1 = z4, gyp2 = z4, gyp3 = z4;
    float4 n0 = z4, n1 = z4, n2 = z4;
    int out_lo = seg * 16, out_hi = out_lo + 15;
    int rs = (out_lo >= 3) ? out_lo - 3 : 0;   // 3-row pipeline warm-up
    int rend = out_hi + 3;                     // 3-step flush
    float msum = 0.f;

    float4 nl = xp[rs << 6];
    for (int r = rs; r <= rend; ++r) {
        int rn = (r + 1 <= 255) ? r + 1 : 255;
        float4 nxt = xp[rn << 6];   // prefetch (clamped; value unused past row 255)
        int r1 = r - 1, r2 = r - 2, r3 = r - 3;
        float4 x1 = stage4(n0,   nl, n0, gyp1, r1, mR3, mL0, lam, del);
        float4 x2 = stage4(cur1, x1, n1, gyp2, r2, mR3, mL0, lam, del);
        float4 x3 = stage4(cur2, x2, n2, gyp3, r3, mR3, mL0, lam, del);
        cur1 = x1; cur2 = x2;
        if (r3 >= out_lo) {   // block-uniform; r3 <= out_hi by loop bound
            uint2 pk;
            pk.x = packbf(x3.x, x3.y);
            pk.y = packbf(x3.z, x3.w);
            *(uint2*)(ap + (r3 << 7)) = pk;
            // mad exchange: publish f32 view row (+ x row), each wave does 64 cols
            *(float4*)&sex[wid + 1][lane * 4] = x3;
            if (wid == 0) *(float4*)&sex[0][lane * 4] = n2;
            __syncthreads();
            int c = wid * 64 + lane;
            float a0 = sex[0][c], a1 = sex[1][c], a2 = sex[2][c],
                  a3 = sex[3][c], a4 = sex[4][c];
            float med = med5f(a0, a1, a2, a3, a4);
            msum += med5f(fabsf(a0 - med), fabsf(a1 - med), fabsf(a2 - med),
                          fabsf(a3 - med), fabsf(a4 - med));
            __syncthreads();   // WAR before next row's publish
        }
        n2 = n1; n1 = n0; n0 = nl;
        nl = nxt;
    }
    #pragma unroll
    for (int off = 32; off > 0; off >>= 1) msum += __shfl_down(msum, off);
    if (lane == 0) red[wid] = msum;
    __syncthreads();
    if (t == 0) atomicAdd(madsum, red[0] + red[1] + red[2] + red[3]);
}

// ---------------- fusion ----------------

__global__ __launch_bounds__(256) void fuse_kernel(
        const float* __restrict__ x, const u32* __restrict__ artsU,
        const float* __restrict__ madsum, float* __restrict__ out) {
    int t = blockIdx.x * 256 + threadIdx.x;
    float floorv = 0.1f * (*madsum) * (1.0f / 6291456.0f);
    float2 xv = ((const float2*)x)[t];
    u32 p0 = artsU[t];
    u32 p1 = artsU[t + NPIX / 2];
    u32 p2 = artsU[t + NPIX];
    u32 p3 = artsU[t + 3 * (NPIX / 2)];
    float2 o;
#define FUSE1(res, A0, SH) { \
        float a0 = A0; \
        float a1 = __uint_as_float(SH(p0)), a2 = __uint_as_float(SH(p1)); \
        float a3 = __uint_as_float(SH(p2)), a4 = __uint_as_float(SH(p3)); \
        float med = med5f(a0, a1, a2, a3, a4); \
        float d0 = fabsf(a0 - med), d1 = fabsf(a1 - med), d2 = fabsf(a2 - med); \
        float d3 = fabsf(a3 - med), d4 = fabsf(a4 - med); \
        float mad = med5f(d0, d1, d2, d3, d4); \
        float mm = fmaxf(mad, floorv); \
        float inv = 0.5f / mm; \
        float w0 = __expf(-d0 * inv), w1 = __expf(-d1 * inv), w2 = __expf(-d2 * inv); \
        float w3 = __expf(-d3 * inv), w4 = __expf(-d4 * inv); \
        float swt = w0 + w1 + w2 + w3 + w4; \
        float sva = fmaf(w0, a0, fmaf(w1, a1, fmaf(w2, a2, fmaf(w3, a3, w4 * a4)))); \
        res = sva / (swt + 1e-8f); \
    }
#define LO16(u) ((u) << 16)
#define HI16(u) ((u) & 0xFFFF0000u)
    FUSE1(o.x, xv.x, LO16);
    FUSE1(o.y, xv.y, HI16);
#undef FUSE1
#undef LO16
#undef HI16
    ((float2*)out)[t] = o;
}

// ---------------- launch ----------------

extern "C" void kernel_launch(void* const* d_in, const int* in_sizes, int n_in,
                              void* d_out, int out_size, void* d_ws, size_t ws_size,
                              hipStream_t stream) {
    const float* x = (const float*)d_in[0];
    float* out = (float*)d_out;
    char* ws = (char*)d_ws;
    float* scale  = (float*)ws;
    float* madsum = (float*)(ws + 128);
    u32* artsU    = (u32*)(ws + 256);

    median_kernel<<<32, 1024, 0, stream>>>(x, scale, madsum);

    float lamf[4], delf[4];
    for (int i = 0; i < 4; ++i) {
        double lam = 0.025 + 0.05 * (double)i / 3.0;
        lamf[i] = (float)lam;
        delf[i] = (float)(0.01 * sqrt(lam / (0.05 + 1e-8)));
    }
    float4 lam4 = make_float4(lamf[0], lamf[1], lamf[2], lamf[3]);
    float4 del4 = make_float4(delf[0], delf[1], delf[2], delf[3]);

    denoise_kernel<<<1536, 256, 0, stream>>>(x, scale, artsU, madsum, lam4, del4);
    fuse_kernel<<<12288, 256, 0, stream>>>(x, artsU, madsum, out);
}